// Round 1
// baseline (790.635 us; speedup 1.0000x reference)
//
#include <hip/hip_runtime.h>
#include <hip/hip_bf16.h>

// GCN 2-layer: out = GCNConv(relu(GCNConv(x, W1, b1)), W2, b2)
// agg[v] = dinv[v] * ( dinv[v]*h[v] + sum_{e: dst=v} dinv[src_e]*h[src_e] ) + b
// deg[v] = 1 + #edges with dst==v (self-loop), dinv = 1/sqrt(deg)

#define D 128

// ---------------- CSR build ----------------

__global__ __launch_bounds__(256) void k_init(int* counts, int* cursor, int n) {
    int i = blockIdx.x * 256 + threadIdx.x;
    if (i < n) { counts[i] = 0; cursor[i] = 0; }
}

__global__ __launch_bounds__(256) void k_count(const int* __restrict__ dst, int* counts, int E) {
    int e = blockIdx.x * 256 + threadIdx.x;
    if (e < E) atomicAdd(&counts[dst[e]], 1);
}

// exclusive scan of counts[0..n) -> rowptr, 3-kernel classic, 4096 elems/block
__global__ __launch_bounds__(256) void k_scan1(const int* __restrict__ counts, int* bsum, int n) {
    int base = blockIdx.x * 4096;
    int s = 0;
    for (int i = threadIdx.x; i < 4096; i += 256) {
        int idx = base + i;
        if (idx < n) s += counts[idx];
    }
    for (int off = 32; off; off >>= 1) s += __shfl_down(s, off);
    __shared__ int ws[4];
    if ((threadIdx.x & 63) == 0) ws[threadIdx.x >> 6] = s;
    __syncthreads();
    if (threadIdx.x == 0) bsum[blockIdx.x] = ws[0] + ws[1] + ws[2] + ws[3];
}

__global__ void k_scan2(int* bsum, int nb, int* rowptr, int n) {
    if (blockIdx.x == 0 && threadIdx.x == 0) {
        int run = 0;
        for (int i = 0; i < nb; i++) { int v = bsum[i]; bsum[i] = run; run += v; }
        rowptr[n] = run;  // == E
    }
}

__global__ __launch_bounds__(256) void k_scan3(const int* __restrict__ counts, const int* __restrict__ bsumEx,
                                               int* __restrict__ rowptr, int n) {
    __shared__ int lds[4096];
    __shared__ int tsum[256];
    int base = blockIdx.x * 4096;
    for (int i = threadIdx.x; i < 4096; i += 256) {
        int idx = base + i;
        lds[i] = (idx < n) ? counts[idx] : 0;
    }
    __syncthreads();
    int t = threadIdx.x;
    int o = t * 16;
    int s = 0;
    #pragma unroll
    for (int i = 0; i < 16; i++) s += lds[o + i];
    tsum[t] = s;
    __syncthreads();
    for (int off = 1; off < 256; off <<= 1) {
        int tmp = 0;
        if (t >= off) tmp = tsum[t - off];
        __syncthreads();
        if (t >= off) tsum[t] += tmp;
        __syncthreads();
    }
    int excl = tsum[t] - s;  // exclusive prefix of this thread's chunk
    int run = bsumEx[blockIdx.x] + excl;
    for (int i = 0; i < 16; i++) {
        int idx = base + o + i;
        if (idx < n) { rowptr[idx] = run; run += lds[o + i]; }
    }
}

__global__ __launch_bounds__(256) void k_dinv(const int* __restrict__ counts, float* __restrict__ dinv, int n) {
    int i = blockIdx.x * 256 + threadIdx.x;
    if (i < n) dinv[i] = 1.0f / sqrtf((float)(counts[i] + 1));  // +1 self-loop
}

__global__ __launch_bounds__(256) void k_fill(const int* __restrict__ src, const int* __restrict__ dst,
                                              const int* __restrict__ rowptr, int* cursor,
                                              int* __restrict__ colidx, int E) {
    int e = blockIdx.x * 256 + threadIdx.x;
    if (e < E) {
        int d = dst[e];
        int p = rowptr[d] + atomicAdd(&cursor[d], 1);
        colidx[p] = src[e];
    }
}

// ---------------- fp32 GEMM: H[n x 128] = X[n x 128] @ W[128 x 128] ----------------
// block: 256 threads, 64 rows. k chunked by 32, W chunk + X chunk in LDS.
// thread (trow=tid>>4, tcol=tid&15) computes rows trow*4+rr (0..63), cols tcol+16*j (0..127).
__global__ __launch_bounds__(256) void k_gemm(const float* __restrict__ X, const float* __restrict__ W,
                                              float* __restrict__ H, int nrows) {
    __shared__ float sW[32 * 128];   // 16 KB
    __shared__ float sX[64 * 33];    // 8.25 KB, row stride 33 breaks bank conflicts
    const int tid = threadIdx.x;
    const int tcol = tid & 15;
    const int trow = tid >> 4;
    const int rowBase = blockIdx.x * 64;

    float acc[4][8];
    #pragma unroll
    for (int i = 0; i < 4; i++)
        #pragma unroll
        for (int j = 0; j < 8; j++) acc[i][j] = 0.f;

    for (int kb = 0; kb < 4; ++kb) {
        // stage W rows [kb*32, kb*32+32) : 4096 floats, 4 float4/thread
        {
            const float4* Wv = (const float4*)(W + kb * 32 * 128);
            float4* sWv = (float4*)sW;
            #pragma unroll
            for (int i = 0; i < 4; i++) sWv[tid + 256 * i] = Wv[tid + 256 * i];
        }
        // stage X tile: 64 rows x 32 cols
        {
            int r = tid >> 2;       // 0..63
            int c4 = tid & 3;       // 0..3
            #pragma unroll
            for (int half = 0; half < 2; ++half) {
                int cc4 = c4 + 4 * half;  // 0..7
                int gr = rowBase + r;
                float4 xv = make_float4(0.f, 0.f, 0.f, 0.f);
                if (gr < nrows) xv = *(const float4*)(X + (size_t)gr * D + kb * 32 + cc4 * 4);
                int c = cc4 * 4;
                sX[r * 33 + c + 0] = xv.x;
                sX[r * 33 + c + 1] = xv.y;
                sX[r * 33 + c + 2] = xv.z;
                sX[r * 33 + c + 3] = xv.w;
            }
        }
        __syncthreads();
        #pragma unroll
        for (int k = 0; k < 32; k++) {
            float xr[4];
            #pragma unroll
            for (int i = 0; i < 4; i++) xr[i] = sX[(trow * 4 + i) * 33 + k];
            #pragma unroll
            for (int j = 0; j < 8; j++) {
                float w = sW[k * 128 + tcol + 16 * j];
                #pragma unroll
                for (int i = 0; i < 4; i++) acc[i][j] += xr[i] * w;
            }
        }
        __syncthreads();
    }
    #pragma unroll
    for (int i = 0; i < 4; i++) {
        int gr = rowBase + trow * 4 + i;
        if (gr < nrows) {
            #pragma unroll
            for (int j = 0; j < 8; j++) H[(size_t)gr * D + tcol + 16 * j] = acc[i][j];
        }
    }
}

// ---------------- CSR aggregation ----------------
// block 256 = 2 nodes x 128 dims; thread d accumulates one output element.
template <bool RELU>
__global__ __launch_bounds__(256) void k_agg(const float* __restrict__ H, const float* __restrict__ dinv,
                                             const int* __restrict__ rowptr, const int* __restrict__ colidx,
                                             const float* __restrict__ bias, float* __restrict__ out, int n) {
    int v = blockIdx.x * 2 + (threadIdx.x >> 7);
    int d = threadIdx.x & 127;
    if (v >= n) return;
    float dv = dinv[v];
    float acc = dv * H[v * D + d];  // self-loop term (gets *dv at end -> dv^2)
    int e = rowptr[v];
    int end = rowptr[v + 1];
    for (; e + 1 < end; e += 2) {
        int s0 = colidx[e];
        int s1 = colidx[e + 1];
        float w0 = dinv[s0];
        float w1 = dinv[s1];
        float h0 = H[s0 * D + d];
        float h1 = H[s1 * D + d];
        acc += w0 * h0;
        acc += w1 * h1;
    }
    if (e < end) {
        int s = colidx[e];
        acc += dinv[s] * H[s * D + d];
    }
    float r = dv * acc + bias[d];
    if (RELU) r = fmaxf(r, 0.f);
    out[v * D + d] = r;
}

// ---------------- launcher ----------------

static inline size_t alignup(size_t x) { return (x + 511) & ~(size_t)511; }

extern "C" void kernel_launch(void* const* d_in, const int* in_sizes, int n_in,
                              void* d_out, int out_size, void* d_ws, size_t ws_size,
                              hipStream_t stream) {
    const float* x  = (const float*)d_in[0];
    const int* eidx = (const int*)d_in[1];   // [2, E] row-major: src then dst
    const float* W1 = (const float*)d_in[2];
    const float* b1 = (const float*)d_in[3];
    const float* W2 = (const float*)d_in[4];
    const float* b2 = (const float*)d_in[5];
    float* out = (float*)d_out;

    const int N = in_sizes[0] / D;
    const int E = in_sizes[1] / 2;
    const int* src = eidx;
    const int* dst = eidx + E;

    // workspace carve-up
    char* ws = (char*)d_ws;
    size_t off = 0;
    int* counts = (int*)(ws + off);   off = alignup(off + (size_t)N * 4);
    int* cursor = (int*)(ws + off);   off = alignup(off + (size_t)N * 4);
    int* rowptr = (int*)(ws + off);   off = alignup(off + (size_t)(N + 1) * 4);
    int* bsum   = (int*)(ws + off);   off = alignup(off + 64 * 4);
    float* dinv = (float*)(ws + off); off = alignup(off + (size_t)N * 4);
    int* colidx = (int*)(ws + off);   off = alignup(off + (size_t)E * 4);
    float* hbuf = (float*)(ws + off); off = alignup(off + (size_t)N * D * 4);
    (void)ws_size;

    const int nThreads = 256;
    const int gN = (N + nThreads - 1) / nThreads;
    const int gE = (E + nThreads - 1) / nThreads;
    const int nScan = (N + 4095) / 4096;

    // CSR build
    k_init<<<gN, nThreads, 0, stream>>>(counts, cursor, N);
    k_count<<<gE, nThreads, 0, stream>>>(dst, counts, E);
    k_scan1<<<nScan, nThreads, 0, stream>>>(counts, bsum, N);
    k_scan2<<<1, 64, 0, stream>>>(bsum, nScan, rowptr, N);
    k_scan3<<<nScan, nThreads, 0, stream>>>(counts, bsum, rowptr, N);
    k_dinv<<<gN, nThreads, 0, stream>>>(counts, dinv, N);
    k_fill<<<gE, nThreads, 0, stream>>>(src, dst, rowptr, cursor, colidx, E);

    const int gGemm = (N + 63) / 64;
    const int gAgg = (N + 1) / 2;

    // layer 1: h1 = x @ W1 -> hbuf ; out (temp) = relu(agg(hbuf) + b1)
    k_gemm<<<gGemm, nThreads, 0, stream>>>(x, W1, hbuf, N);
    k_agg<true><<<gAgg, nThreads, 0, stream>>>(hbuf, dinv, rowptr, colidx, b1, out, N);

    // layer 2: h2 = out @ W2 -> hbuf ; out = agg(hbuf) + b2
    k_gemm<<<gGemm, nThreads, 0, stream>>>(out, W2, hbuf, N);
    k_agg<false><<<gAgg, nThreads, 0, stream>>>(hbuf, dinv, rowptr, colidx, b2, out, N);
}

// Round 2
// 523.283 us; speedup vs baseline: 1.5109x; 1.5109x over previous
//
#include <hip/hip_runtime.h>
#include <hip/hip_bf16.h>

// GCN 2-layer: out = GCNConv(relu(GCNConv(x, W1, b1)), W2, b2)
// agg[v] = dinv[v] * ( dinv[v]*h[v] + sum_{e: dst=v} dinv[src_e]*h[src_e] ) + b
// deg[v] = 1 + #edges with dst==v (self-loop), dinv = 1/sqrt(deg)
// hbuf (GEMM output, gather operand) stored bf16 to halve gather traffic;
// all accumulation fp32.

#define D 128

// ---------------- CSR build ----------------

__global__ __launch_bounds__(256) void k_count(const int* __restrict__ dst, int* counts, int E) {
    int i = blockIdx.x * 256 + threadIdx.x;
    int e = i * 4;
    if (e + 3 < E) {
        int4 d4 = ((const int4*)dst)[i];
        atomicAdd(&counts[d4.x], 1);
        atomicAdd(&counts[d4.y], 1);
        atomicAdd(&counts[d4.z], 1);
        atomicAdd(&counts[d4.w], 1);
    } else {
        for (int k = e; k < E; k++) atomicAdd(&counts[dst[k]], 1);
    }
}

// exclusive scan of counts[0..n) -> rowptr, 3-kernel classic, 4096 elems/block
__global__ __launch_bounds__(256) void k_scan1(const int* __restrict__ counts, int* bsum, int n) {
    int base = blockIdx.x * 4096;
    int s = 0;
    for (int i = threadIdx.x; i < 4096; i += 256) {
        int idx = base + i;
        if (idx < n) s += counts[idx];
    }
    for (int off = 32; off; off >>= 1) s += __shfl_down(s, off);
    __shared__ int ws[4];
    if ((threadIdx.x & 63) == 0) ws[threadIdx.x >> 6] = s;
    __syncthreads();
    if (threadIdx.x == 0) bsum[blockIdx.x] = ws[0] + ws[1] + ws[2] + ws[3];
}

__global__ void k_scan2(int* bsum, int nb, int* rowptr, int n) {
    if (blockIdx.x == 0 && threadIdx.x == 0) {
        int run = 0;
        for (int i = 0; i < nb; i++) { int v = bsum[i]; bsum[i] = run; run += v; }
        rowptr[n] = run;  // == E
    }
}

// scan3 also emits dinv (counts already staged in LDS)
__global__ __launch_bounds__(256) void k_scan3(const int* __restrict__ counts, const int* __restrict__ bsumEx,
                                               int* __restrict__ rowptr, float* __restrict__ dinv, int n) {
    __shared__ int lds[4096];
    __shared__ int tsum[256];
    int base = blockIdx.x * 4096;
    for (int i = threadIdx.x; i < 4096; i += 256) {
        int idx = base + i;
        lds[i] = (idx < n) ? counts[idx] : 0;
    }
    __syncthreads();
    int t = threadIdx.x;
    int o = t * 16;
    int s = 0;
    #pragma unroll
    for (int i = 0; i < 16; i++) s += lds[o + i];
    tsum[t] = s;
    __syncthreads();
    for (int off = 1; off < 256; off <<= 1) {
        int tmp = 0;
        if (t >= off) tmp = tsum[t - off];
        __syncthreads();
        if (t >= off) tsum[t] += tmp;
        __syncthreads();
    }
    int excl = tsum[t] - s;
    int run = bsumEx[blockIdx.x] + excl;
    for (int i = 0; i < 16; i++) {
        int idx = base + o + i;
        if (idx < n) {
            rowptr[idx] = run;
            run += lds[o + i];
            dinv[idx] = 1.0f / sqrtf((float)(lds[o + i] + 1));  // +1 self-loop
        }
    }
}

// fill packed edges: {src, dinv[src]} so agg needs no dependent dinv load
__global__ __launch_bounds__(256) void k_fill(const int* __restrict__ src, const int* __restrict__ dst,
                                              const int* __restrict__ rowptr, const float* __restrict__ dinv,
                                              int* cursor, int2* __restrict__ epack, int E) {
    int e = blockIdx.x * 256 + threadIdx.x;
    if (e < E) {
        int s = src[e];
        int d = dst[e];
        int p = rowptr[d] + atomicAdd(&cursor[d], 1);
        epack[p] = make_int2(s, __float_as_int(dinv[s]));
    }
}

// ---------------- fp32 GEMM: Hb[n x 128](bf16) = X[n x 128] @ W[128 x 128] ----------------
__global__ __launch_bounds__(256) void k_gemm(const float* __restrict__ X, const float* __restrict__ W,
                                              ushort* __restrict__ Hb, int nrows) {
    __shared__ float sW[32 * 128];   // 16 KB
    __shared__ float sX[64 * 33];    // 8.25 KB, stride 33 breaks conflicts
    const int tid = threadIdx.x;
    const int tcol = tid & 15;
    const int trow = tid >> 4;
    const int rowBase = blockIdx.x * 64;

    float acc[4][8];
    #pragma unroll
    for (int i = 0; i < 4; i++)
        #pragma unroll
        for (int j = 0; j < 8; j++) acc[i][j] = 0.f;

    for (int kb = 0; kb < 4; ++kb) {
        {
            const float4* Wv = (const float4*)(W + kb * 32 * 128);
            float4* sWv = (float4*)sW;
            #pragma unroll
            for (int i = 0; i < 4; i++) sWv[tid + 256 * i] = Wv[tid + 256 * i];
        }
        {
            int r = tid >> 2;
            int c4 = tid & 3;
            #pragma unroll
            for (int half = 0; half < 2; ++half) {
                int cc4 = c4 + 4 * half;
                int gr = rowBase + r;
                float4 xv = make_float4(0.f, 0.f, 0.f, 0.f);
                if (gr < nrows) xv = *(const float4*)(X + (size_t)gr * D + kb * 32 + cc4 * 4);
                int c = cc4 * 4;
                sX[r * 33 + c + 0] = xv.x;
                sX[r * 33 + c + 1] = xv.y;
                sX[r * 33 + c + 2] = xv.z;
                sX[r * 33 + c + 3] = xv.w;
            }
        }
        __syncthreads();
        #pragma unroll
        for (int k = 0; k < 32; k++) {
            float xr[4];
            #pragma unroll
            for (int i = 0; i < 4; i++) xr[i] = sX[(trow * 4 + i) * 33 + k];
            #pragma unroll
            for (int j = 0; j < 8; j++) {
                float w = sW[k * 128 + tcol + 16 * j];
                #pragma unroll
                for (int i = 0; i < 4; i++) acc[i][j] += xr[i] * w;
            }
        }
        __syncthreads();
    }
    #pragma unroll
    for (int i = 0; i < 4; i++) {
        int gr = rowBase + trow * 4 + i;
        if (gr < nrows) {
            #pragma unroll
            for (int j = 0; j < 8; j++) {
                __hip_bfloat16 b = __float2bfloat16(acc[i][j]);
                Hb[(size_t)gr * D + tcol + 16 * j] = *reinterpret_cast<ushort*>(&b);
            }
        }
    }
}

// ---------------- CSR aggregation (bf16 gather, fp32 accumulate) ----------------
// one node per 64-lane wave; lane handles dims {2*lane, 2*lane+1} via bf16x2 word.
template <bool RELU>
__global__ __launch_bounds__(256) void k_agg(const ushort* __restrict__ Hb, const float* __restrict__ dinv,
                                             const int* __restrict__ rowptr, const int2* __restrict__ epack,
                                             const float* __restrict__ bias, float* __restrict__ out, int n) {
    int v = blockIdx.x * 4 + (threadIdx.x >> 6);
    int lane = threadIdx.x & 63;
    if (v >= n) return;
    float dv = dinv[v];
    const uint* __restrict__ Hu = (const uint*)Hb;
    uint hs = Hu[(size_t)v * 64 + lane];
    float ax = dv * __uint_as_float(hs << 16);
    float ay = dv * __uint_as_float(hs & 0xffff0000u);
    int e = rowptr[v];
    const int end = rowptr[v + 1];
    for (; e + 7 < end; e += 8) {
        int2 p[8];
        #pragma unroll
        for (int i = 0; i < 8; i++) p[i] = epack[e + i];
        uint h[8];
        #pragma unroll
        for (int i = 0; i < 8; i++) h[i] = Hu[(size_t)p[i].x * 64 + lane];
        #pragma unroll
        for (int i = 0; i < 8; i++) {
            float w = __int_as_float(p[i].y);
            ax += w * __uint_as_float(h[i] << 16);
            ay += w * __uint_as_float(h[i] & 0xffff0000u);
        }
    }
    for (; e + 3 < end; e += 4) {
        int2 p[4];
        #pragma unroll
        for (int i = 0; i < 4; i++) p[i] = epack[e + i];
        uint h[4];
        #pragma unroll
        for (int i = 0; i < 4; i++) h[i] = Hu[(size_t)p[i].x * 64 + lane];
        #pragma unroll
        for (int i = 0; i < 4; i++) {
            float w = __int_as_float(p[i].y);
            ax += w * __uint_as_float(h[i] << 16);
            ay += w * __uint_as_float(h[i] & 0xffff0000u);
        }
    }
    for (; e < end; ++e) {
        int2 pp = epack[e];
        uint hh = Hu[(size_t)pp.x * 64 + lane];
        float w = __int_as_float(pp.y);
        ax += w * __uint_as_float(hh << 16);
        ay += w * __uint_as_float(hh & 0xffff0000u);
    }
    float2 bb = ((const float2*)bias)[lane];
    float rx = dv * ax + bb.x;
    float ry = dv * ay + bb.y;
    if (RELU) { rx = fmaxf(rx, 0.f); ry = fmaxf(ry, 0.f); }
    ((float2*)(out + (size_t)v * 128))[lane] = make_float2(rx, ry);
}

// ---------------- launcher ----------------

static inline size_t alignup(size_t x) { return (x + 511) & ~(size_t)511; }

extern "C" void kernel_launch(void* const* d_in, const int* in_sizes, int n_in,
                              void* d_out, int out_size, void* d_ws, size_t ws_size,
                              hipStream_t stream) {
    const float* x  = (const float*)d_in[0];
    const int* eidx = (const int*)d_in[1];   // [2, E]: src row then dst row (int32 from harness)
    const float* W1 = (const float*)d_in[2];
    const float* b1 = (const float*)d_in[3];
    const float* W2 = (const float*)d_in[4];
    const float* b2 = (const float*)d_in[5];
    float* out = (float*)d_out;

    const int N = in_sizes[0] / D;
    const int E = in_sizes[1] / 2;
    const int* src = eidx;
    const int* dst = eidx + E;

    // workspace carve-up
    char* ws = (char*)d_ws;
    size_t off = 0;
    size_t counts_off = off;
    int* counts = (int*)(ws + off);   off = alignup(off + (size_t)N * 4);
    int* cursor = (int*)(ws + off);   off = alignup(off + (size_t)N * 4);
    size_t zero_span = off - counts_off;  // counts + cursor (incl. pad)
    int* rowptr = (int*)(ws + off);   off = alignup(off + (size_t)(N + 1) * 4);
    int* bsum   = (int*)(ws + off);   off = alignup(off + 64 * 4);
    float* dinv = (float*)(ws + off); off = alignup(off + (size_t)N * 4);
    int2* epack = (int2*)(ws + off);  off = alignup(off + (size_t)E * 8);
    ushort* hbuf = (ushort*)(ws + off); off = alignup(off + (size_t)N * D * 2);
    (void)ws_size;

    const int nT = 256;
    const int gE = (E + nT - 1) / nT;
    const int gE4 = (E / 4 + nT - 1) / nT;
    const int nScan = (N + 4095) / 4096;

    // CSR build
    hipMemsetAsync(ws + counts_off, 0, zero_span, stream);
    k_count<<<gE4, nT, 0, stream>>>(dst, counts, E);
    k_scan1<<<nScan, nT, 0, stream>>>(counts, bsum, N);
    k_scan2<<<1, 64, 0, stream>>>(bsum, nScan, rowptr, N);
    k_scan3<<<nScan, nT, 0, stream>>>(counts, bsum, rowptr, dinv, N);
    k_fill<<<gE, nT, 0, stream>>>(src, dst, rowptr, dinv, cursor, epack, E);

    const int gGemm = (N + 63) / 64;
    const int gAgg = (N + 3) / 4;

    // layer 1: hbuf = bf16(x @ W1); out(temp) = relu(agg(hbuf) + b1)
    k_gemm<<<gGemm, nT, 0, stream>>>(x, W1, hbuf, N);
    k_agg<true><<<gAgg, nT, 0, stream>>>(hbuf, dinv, rowptr, epack, b1, out, N);

    // layer 2: hbuf = bf16(out @ W2); out = agg(hbuf) + b2
    k_gemm<<<gGemm, nT, 0, stream>>>(out, W2, hbuf, N);
    k_agg<false><<<gAgg, nT, 0, stream>>>(hbuf, dinv, rowptr, epack, b2, out, N);
}

// Round 3
// 482.653 us; speedup vs baseline: 1.6381x; 1.0842x over previous
//
#include <hip/hip_runtime.h>
#include <hip/hip_bf16.h>

// GCN 2-layer. agg[v] = dinv[v]*(dinv[v]*h[v] + sum_e dinv[src]*h[src]) + b
// CSR built per call via bucket-binned counting sort (write-inflation fix).
// GEMMs via bf16 MFMA 16x16x32 (fp32 load, in-register convert, fp32 acc).

#define D 128
#define NBLK_S 1024   // hist/scatter blocks (tab stride)
#define MAXBUK 128    // buckets of 1024 nodes; N <= 131072

typedef __attribute__((ext_vector_type(8))) short short8;
typedef __attribute__((ext_vector_type(4))) float f32x4;

static __device__ __forceinline__ ushort f2b(float f) {
    __hip_bfloat16 h = __float2bfloat16(f);
    return *reinterpret_cast<ushort*>(&h);
}

// ---------------- CSR build ----------------

// per-node counts (global atomics) + per-(block,bucket) histogram
__global__ __launch_bounds__(256) void k_hist(const int* __restrict__ dst, int* __restrict__ counts,
                                              int* __restrict__ tab, int E, int chunk, int nbuk) {
    __shared__ int lh[MAXBUK];
    for (int i = threadIdx.x; i < nbuk; i += 256) lh[i] = 0;
    __syncthreads();
    int start = blockIdx.x * chunk;
    int end = min(E, start + chunk);
    for (int e = start + threadIdx.x; e < end; e += 256) {
        int d = dst[e];
        atomicAdd(&counts[d], 1);
        atomicAdd(&lh[d >> 10], 1);
    }
    __syncthreads();
    for (int i = threadIdx.x; i < nbuk; i += 256) tab[(i << 10) | blockIdx.x] = lh[i];
}

// exclusive scan of counts -> rowptr (3-kernel), scan3 also emits dinv
__global__ __launch_bounds__(256) void k_scan1(const int* __restrict__ counts, int* bsum, int n) {
    int base = blockIdx.x * 4096;
    int s = 0;
    for (int i = threadIdx.x; i < 4096; i += 256) {
        int idx = base + i;
        if (idx < n) s += counts[idx];
    }
    for (int off = 32; off; off >>= 1) s += __shfl_down(s, off);
    __shared__ int wsum[4];
    if ((threadIdx.x & 63) == 0) wsum[threadIdx.x >> 6] = s;
    __syncthreads();
    if (threadIdx.x == 0) bsum[blockIdx.x] = wsum[0] + wsum[1] + wsum[2] + wsum[3];
}

__global__ void k_scan2(int* bsum, int nb, int* rowptr, int n) {
    if (blockIdx.x == 0 && threadIdx.x == 0) {
        int run = 0;
        for (int i = 0; i < nb; i++) { int v = bsum[i]; bsum[i] = run; run += v; }
        rowptr[n] = run;  // == E
    }
}

__global__ __launch_bounds__(256) void k_scan3(const int* __restrict__ counts, const int* __restrict__ bsumEx,
                                               int* __restrict__ rowptr, float* __restrict__ dinv, int n) {
    __shared__ int lds[4096];
    __shared__ int tsum[256];
    int base = blockIdx.x * 4096;
    for (int i = threadIdx.x; i < 4096; i += 256) {
        int idx = base + i;
        lds[i] = (idx < n) ? counts[idx] : 0;
    }
    __syncthreads();
    int t = threadIdx.x;
    int o = t * 16;
    int s = 0;
    #pragma unroll
    for (int i = 0; i < 16; i++) s += lds[o + i];
    tsum[t] = s;
    __syncthreads();
    for (int off = 1; off < 256; off <<= 1) {
        int tmp = 0;
        if (t >= off) tmp = tsum[t - off];
        __syncthreads();
        if (t >= off) tsum[t] += tmp;
        __syncthreads();
    }
    int excl = tsum[t] - s;
    int run = bsumEx[blockIdx.x] + excl;
    for (int i = 0; i < 16; i++) {
        int idx = base + o + i;
        if (idx < n) {
            rowptr[idx] = run;
            run += lds[o + i];
            dinv[idx] = 1.0f / sqrtf((float)(lds[o + i] + 1));  // +1 self-loop
        }
    }
}

// per-bucket exclusive scan over blocks; bucket base = rowptr[b<<10]
__global__ __launch_bounds__(128) void k_scanT(int* __restrict__ tab, const int* __restrict__ rowptr, int nbuk) {
    int b = threadIdx.x;
    if (b >= nbuk) return;
    int base = rowptr[b << 10];
    int* t = tab + (b << 10);
    for (int blk = 0; blk < NBLK_S; blk++) { int c = t[blk]; t[blk] = base; base += c; }
}

// edges -> bucket-ordered tmp; packed (dstLow<<22)|src  (src < 2^22)
__global__ __launch_bounds__(256) void k_scatter(const int* __restrict__ src, const int* __restrict__ dst,
                                                 const int* __restrict__ tab, uint* __restrict__ tmp,
                                                 int E, int chunk, int nbuk) {
    __shared__ int cur[MAXBUK];
    for (int i = threadIdx.x; i < nbuk; i += 256) cur[i] = tab[(i << 10) | blockIdx.x];
    __syncthreads();
    int start = blockIdx.x * chunk;
    int end = min(E, start + chunk);
    for (int e = start + threadIdx.x; e < end; e += 256) {
        int s = src[e];
        int d = dst[e];
        int pos = atomicAdd(&cur[d >> 10], 1);
        tmp[pos] = ((uint)(d & 1023) << 22) | (uint)s;
    }
}

// bucket-local fill: LDS cursors + rowptr slice; epack writes in 131 KB window
__global__ __launch_bounds__(256) void k_fillC(const uint* __restrict__ tmp, const int* __restrict__ rowptr,
                                               const float* __restrict__ dinv, int2* __restrict__ epack,
                                               int n) {
    __shared__ int rp[1025];
    __shared__ int cur[1024];
    int node0 = blockIdx.x << 10;
    int nn = min(1024, n - node0);
    for (int i = threadIdx.x; i < nn + 1; i += 256) rp[i] = rowptr[node0 + i];
    for (int i = threadIdx.x; i < nn; i += 256) cur[i] = 0;
    __syncthreads();
    int e0 = rp[0], e1 = rp[nn];
    for (int e = e0 + threadIdx.x; e < e1; e += 256) {
        uint u = tmp[e];
        int dLow = (int)(u >> 22);
        int s = (int)(u & 0x3FFFFFu);
        int rank = atomicAdd(&cur[dLow], 1);
        epack[rp[dLow] + rank] = make_int2(s, __float_as_int(dinv[s]));
    }
}

// ---------------- W prep: transpose + bf16 (Wt[n][k]) ----------------
__global__ __launch_bounds__(256) void k_prepW(const float* __restrict__ W1, const float* __restrict__ W2,
                                               ushort* __restrict__ Wt1, ushort* __restrict__ Wt2) {
    int i = blockIdx.x * 256 + threadIdx.x;   // i over 128*128
    if (i < 16384) {
        int kk = i >> 7, nn = i & 127;
        Wt1[nn * 128 + kk] = f2b(W1[i]);
        Wt2[nn * 128 + kk] = f2b(W2[i]);
    }
}

// ---------------- MFMA GEMM: Hb[n x 128](bf16) = X[n x 128](fp32) @ W ----------------
// wave = 16 rows x 128 cols (8 col-tiles); block = 4 waves = 64 rows.
// verified layouts: A[m=lane&15][k=quad*8+j]; B[k=quad*8+j][n=lane&15]; D col=lane&15,row=quad*4+r
__global__ __launch_bounds__(256) void k_gemm(const float* __restrict__ X, const ushort* __restrict__ Wt,
                                              ushort* __restrict__ Hb, int nrows) {
    const int wave = threadIdx.x >> 6;
    const int lane = threadIdx.x & 63;
    const int quad = lane >> 4;
    const int m = lane & 15;
    const int row0 = blockIdx.x * 64 + wave * 16;
    const int rowc = min(row0 + m, nrows - 1);

    f32x4 acc[8];
    #pragma unroll
    for (int t = 0; t < 8; t++) acc[t] = (f32x4){0.f, 0.f, 0.f, 0.f};

    #pragma unroll
    for (int ks = 0; ks < 4; ks++) {
        const int k0 = ks * 32 + quad * 8;
        const float* p = X + (size_t)rowc * D + k0;
        float4 u0 = ((const float4*)p)[0];
        float4 u1 = ((const float4*)p)[1];
        short8 a;
        a[0] = (short)f2b(u0.x); a[1] = (short)f2b(u0.y);
        a[2] = (short)f2b(u0.z); a[3] = (short)f2b(u0.w);
        a[4] = (short)f2b(u1.x); a[5] = (short)f2b(u1.y);
        a[6] = (short)f2b(u1.z); a[7] = (short)f2b(u1.w);
        #pragma unroll
        for (int t = 0; t < 8; t++) {
            short8 b = *(const short8*)(Wt + ((t * 16 + m) * D + k0));
            acc[t] = __builtin_amdgcn_mfma_f32_16x16x32_bf16(a, b, acc[t], 0, 0, 0);
        }
    }
    #pragma unroll
    for (int r = 0; r < 4; r++) {
        int orow = row0 + quad * 4 + r;
        if (orow < nrows) {
            #pragma unroll
            for (int t = 0; t < 8; t++)
                Hb[(size_t)orow * D + t * 16 + m] = f2b(acc[t][r]);
        }
    }
}

// ---------------- CSR aggregation (bf16 gather, fp32 accumulate) ----------------
template <bool RELU>
__global__ __launch_bounds__(256) void k_agg(const ushort* __restrict__ Hb, const float* __restrict__ dinv,
                                             const int* __restrict__ rowptr, const int2* __restrict__ epack,
                                             const float* __restrict__ bias, float* __restrict__ out, int n) {
    int v = blockIdx.x * 4 + (threadIdx.x >> 6);
    int lane = threadIdx.x & 63;
    if (v >= n) return;
    float dv = dinv[v];
    const uint* __restrict__ Hu = (const uint*)Hb;
    uint hs = Hu[(size_t)v * 64 + lane];
    float ax = dv * __uint_as_float(hs << 16);
    float ay = dv * __uint_as_float(hs & 0xffff0000u);
    int e = rowptr[v];
    const int end = rowptr[v + 1];
    for (; e + 7 < end; e += 8) {
        int2 p[8];
        #pragma unroll
        for (int i = 0; i < 8; i++) p[i] = epack[e + i];
        uint h[8];
        #pragma unroll
        for (int i = 0; i < 8; i++) h[i] = Hu[(size_t)p[i].x * 64 + lane];
        #pragma unroll
        for (int i = 0; i < 8; i++) {
            float w = __int_as_float(p[i].y);
            ax += w * __uint_as_float(h[i] << 16);
            ay += w * __uint_as_float(h[i] & 0xffff0000u);
        }
    }
    for (; e + 3 < end; e += 4) {
        int2 p[4];
        #pragma unroll
        for (int i = 0; i < 4; i++) p[i] = epack[e + i];
        uint h[4];
        #pragma unroll
        for (int i = 0; i < 4; i++) h[i] = Hu[(size_t)p[i].x * 64 + lane];
        #pragma unroll
        for (int i = 0; i < 4; i++) {
            float w = __int_as_float(p[i].y);
            ax += w * __uint_as_float(h[i] << 16);
            ay += w * __uint_as_float(h[i] & 0xffff0000u);
        }
    }
    for (; e < end; ++e) {
        int2 pp = epack[e];
        uint hh = Hu[(size_t)pp.x * 64 + lane];
        float w = __int_as_float(pp.y);
        ax += w * __uint_as_float(hh << 16);
        ay += w * __uint_as_float(hh & 0xffff0000u);
    }
    float2 bb = ((const float2*)bias)[lane];
    float rx = dv * ax + bb.x;
    float ry = dv * ay + bb.y;
    if (RELU) { rx = fmaxf(rx, 0.f); ry = fmaxf(ry, 0.f); }
    ((float2*)(out + (size_t)v * D))[lane] = make_float2(rx, ry);
}

// ---------------- launcher ----------------

static inline size_t alignup(size_t x) { return (x + 511) & ~(size_t)511; }

extern "C" void kernel_launch(void* const* d_in, const int* in_sizes, int n_in,
                              void* d_out, int out_size, void* d_ws, size_t ws_size,
                              hipStream_t stream) {
    const float* x  = (const float*)d_in[0];
    const int* eidx = (const int*)d_in[1];   // [2,E]: src row, dst row (int32)
    const float* W1 = (const float*)d_in[2];
    const float* b1 = (const float*)d_in[3];
    const float* W2 = (const float*)d_in[4];
    const float* b2 = (const float*)d_in[5];
    float* out = (float*)d_out;

    const int N = in_sizes[0] / D;
    const int E = in_sizes[1] / 2;
    const int* src = eidx;
    const int* dst = eidx + E;
    const int nbuk = (N + 1023) >> 10;          // 98
    const int chunk = (E + NBLK_S - 1) / NBLK_S; // 1563

    // workspace
    char* ws = (char*)d_ws;
    size_t off = 0;
    int* counts = (int*)(ws + off);   off = alignup(off + (size_t)N * 4);
    int* rowptr = (int*)(ws + off);   off = alignup(off + (size_t)(N + 1) * 4);
    int* bsum   = (int*)(ws + off);   off = alignup(off + 256 * 4);
    float* dinv = (float*)(ws + off); off = alignup(off + (size_t)N * 4);
    int* tab    = (int*)(ws + off);   off = alignup(off + (size_t)MAXBUK * NBLK_S * 4);
    int2* epack = (int2*)(ws + off);  off = alignup(off + (size_t)E * 8);
    ushort* hbuf = (ushort*)(ws + off); off = alignup(off + (size_t)N * D * 2);
    ushort* Wt1 = (ushort*)(ws + off); off = alignup(off + 16384 * 2);
    ushort* Wt2 = (ushort*)(ws + off); off = alignup(off + 16384 * 2);
    uint* tmp = (uint*)hbuf;  // tmp (E uints = 6.4MB) aliases hbuf; dead before gemm1 writes
    (void)ws_size;

    const int nT = 256;
    const int nScan = (N + 4095) / 4096;

    hipMemsetAsync(counts, 0, (size_t)N * 4, stream);
    k_prepW<<<64, nT, 0, stream>>>(W1, W2, Wt1, Wt2);
    k_hist<<<NBLK_S, nT, 0, stream>>>(dst, counts, tab, E, chunk, nbuk);
    k_scan1<<<nScan, nT, 0, stream>>>(counts, bsum, N);
    k_scan2<<<1, 64, 0, stream>>>(bsum, nScan, rowptr, N);
    k_scan3<<<nScan, nT, 0, stream>>>(counts, bsum, rowptr, dinv, N);
    k_scanT<<<1, 128, 0, stream>>>(tab, rowptr, nbuk);
    k_scatter<<<NBLK_S, nT, 0, stream>>>(src, dst, tab, tmp, E, chunk, nbuk);
    k_fillC<<<nbuk, nT, 0, stream>>>(tmp, rowptr, dinv, epack, N);

    const int gGemm = (N + 63) / 64;
    const int gAgg = (N + 3) / 4;

    // layer 1: hbuf = bf16(x @ W1); d_out(temp fp32) = relu(agg(hbuf) + b1)
    k_gemm<<<gGemm, nT, 0, stream>>>(x, Wt1, hbuf, N);
    k_agg<true><<<gAgg, nT, 0, stream>>>(hbuf, dinv, rowptr, epack, b1, out, N);

    // layer 2: hbuf = bf16(out @ W2); out = agg(hbuf) + b2
    k_gemm<<<gGemm, nT, 0, stream>>>(out, Wt2, hbuf, N);
    k_agg<false><<<gAgg, nT, 0, stream>>>(hbuf, dinv, rowptr, epack, b2, out, N);
}

// Round 4
// 438.216 us; speedup vs baseline: 1.8042x; 1.1014x over previous
//
#include <hip/hip_runtime.h>
#include <hip/hip_bf16.h>

// GCN 2-layer. agg[v] = dinv[v]*(dinv[v]*h[v] + sum_e dinv[src]*h[src]) + b
// CSR via bucket-binned counting sort with atomic range reservation
// (no per-(block,bucket) table, no serial table scan).
// GEMMs via bf16 MFMA 16x16x32 (fp32 load, in-register convert, fp32 acc).

#define D 128
#define BUKBITS 7          // 128 nodes per bucket
#define BUKSZ 128
#define MAXBUK 1024        // supports N <= 131072
#define SC_ITER 16         // edges per thread in scatter (block chunk = 4096)

typedef __attribute__((ext_vector_type(8))) short short8;
typedef __attribute__((ext_vector_type(4))) float f32x4;

static __device__ __forceinline__ ushort f2b(float f) {
    __hip_bfloat16 h = __float2bfloat16(f);
    return *reinterpret_cast<ushort*>(&h);
}

// ---------------- CSR build ----------------

// per-node degree counts
__global__ __launch_bounds__(256) void k_hist(const int* __restrict__ dst, int* __restrict__ counts, int E) {
    int i = blockIdx.x * 256 + threadIdx.x;
    int e = i * 4;
    if (e + 3 < E) {
        int4 d4 = ((const int4*)dst)[i];
        atomicAdd(&counts[d4.x], 1);
        atomicAdd(&counts[d4.y], 1);
        atomicAdd(&counts[d4.z], 1);
        atomicAdd(&counts[d4.w], 1);
    } else {
        for (int k = e; k < E; k++) atomicAdd(&counts[dst[k]], 1);
    }
}

// exclusive scan of counts -> rowptr (3-kernel), scan3 also emits dinv
__global__ __launch_bounds__(256) void k_scan1(const int* __restrict__ counts, int* bsum, int n) {
    int base = blockIdx.x * 4096;
    int s = 0;
    for (int i = threadIdx.x; i < 4096; i += 256) {
        int idx = base + i;
        if (idx < n) s += counts[idx];
    }
    for (int off = 32; off; off >>= 1) s += __shfl_down(s, off);
    __shared__ int wsum[4];
    if ((threadIdx.x & 63) == 0) wsum[threadIdx.x >> 6] = s;
    __syncthreads();
    if (threadIdx.x == 0) bsum[blockIdx.x] = wsum[0] + wsum[1] + wsum[2] + wsum[3];
}

__global__ void k_scan2(int* bsum, int nb, int* rowptr, int n) {
    if (blockIdx.x == 0 && threadIdx.x == 0) {
        int run = 0;
        for (int i = 0; i < nb; i++) { int v = bsum[i]; bsum[i] = run; run += v; }
        rowptr[n] = run;  // == E
    }
}

__global__ __launch_bounds__(256) void k_scan3(const int* __restrict__ counts, const int* __restrict__ bsumEx,
                                               int* __restrict__ rowptr, float* __restrict__ dinv, int n) {
    __shared__ int lds[4096];
    __shared__ int tsum[256];
    int base = blockIdx.x * 4096;
    for (int i = threadIdx.x; i < 4096; i += 256) {
        int idx = base + i;
        lds[i] = (idx < n) ? counts[idx] : 0;
    }
    __syncthreads();
    int t = threadIdx.x;
    int o = t * 16;
    int s = 0;
    #pragma unroll
    for (int i = 0; i < 16; i++) s += lds[o + i];
    tsum[t] = s;
    __syncthreads();
    for (int off = 1; off < 256; off <<= 1) {
        int tmpv = 0;
        if (t >= off) tmpv = tsum[t - off];
        __syncthreads();
        if (t >= off) tsum[t] += tmpv;
        __syncthreads();
    }
    int excl = tsum[t] - s;
    int run = bsumEx[blockIdx.x] + excl;
    for (int i = 0; i < 16; i++) {
        int idx = base + o + i;
        if (idx < n) {
            rowptr[idx] = run;
            run += lds[o + i];
            dinv[idx] = 1.0f / sqrtf((float)(lds[o + i] + 1));  // +1 self-loop
        }
    }
}

// bucket cursors init: gcur[b] = rowptr[b << BUKBITS]
__global__ __launch_bounds__(256) void k_gcur(const int* __restrict__ rowptr, int* __restrict__ gcur, int nbuk) {
    int b = blockIdx.x * 256 + threadIdx.x;
    if (b < nbuk) gcur[b] = rowptr[b << BUKBITS];
}

// edges -> bucket-grouped tmp via LDS hist + global range reservation.
// tmp payload: (dstLow << 22) | src   (src < 2^22)
__global__ __launch_bounds__(256) void k_scatter(const int* __restrict__ src, const int* __restrict__ dst,
                                                 int* __restrict__ gcur, uint* __restrict__ tmp,
                                                 int E, int nbuk) {
    __shared__ int lh[MAXBUK];
    __shared__ int lbase[MAXBUK];
    for (int i = threadIdx.x; i < nbuk; i += 256) lh[i] = 0;
    __syncthreads();
    const int start = blockIdx.x * (256 * SC_ITER);
    int sarr[SC_ITER], darr[SC_ITER], rank[SC_ITER];
    #pragma unroll
    for (int i = 0; i < SC_ITER; i++) {
        int e = start + i * 256 + threadIdx.x;
        darr[i] = -1;
        if (e < E) {
            sarr[i] = src[e];
            darr[i] = dst[e];
            rank[i] = atomicAdd(&lh[darr[i] >> BUKBITS], 1);
        }
    }
    __syncthreads();
    for (int b = threadIdx.x; b < nbuk; b += 256) {
        int c = lh[b];
        lbase[b] = (c > 0) ? atomicAdd(&gcur[b], c) : 0;
    }
    __syncthreads();
    #pragma unroll
    for (int i = 0; i < SC_ITER; i++) {
        if (darr[i] >= 0) {
            int b = darr[i] >> BUKBITS;
            tmp[lbase[b] + rank[i]] = ((uint)(darr[i] & (BUKSZ - 1)) << 22) | (uint)sarr[i];
        }
    }
}

// bucket-local fill: LDS cursors + rowptr slice; epack writes in ~16 KB window
__global__ __launch_bounds__(256) void k_fillC(const uint* __restrict__ tmp, const int* __restrict__ rowptr,
                                               const float* __restrict__ dinv, int2* __restrict__ epack,
                                               int n) {
    __shared__ int rp[BUKSZ + 1];
    __shared__ int cur[BUKSZ];
    int node0 = blockIdx.x << BUKBITS;
    int nn = min(BUKSZ, n - node0);
    if (threadIdx.x < nn + 1) rp[threadIdx.x] = rowptr[node0 + threadIdx.x];
    if (threadIdx.x < nn) cur[threadIdx.x] = 0;
    __syncthreads();
    int e0 = rp[0], e1 = rp[nn];
    for (int e = e0 + threadIdx.x; e < e1; e += 256) {
        uint u = tmp[e];
        int dLow = (int)(u >> 22);
        int s = (int)(u & 0x3FFFFFu);
        int rank = atomicAdd(&cur[dLow], 1);
        epack[rp[dLow] + rank] = make_int2(s, __float_as_int(dinv[s]));
    }
}

// ---------------- W prep: transpose + bf16 (Wt[n][k]) ----------------
__global__ __launch_bounds__(256) void k_prepW(const float* __restrict__ W1, const float* __restrict__ W2,
                                               ushort* __restrict__ Wt1, ushort* __restrict__ Wt2) {
    int i = blockIdx.x * 256 + threadIdx.x;
    if (i < 16384) {
        int kk = i >> 7, nn = i & 127;
        Wt1[nn * 128 + kk] = f2b(W1[i]);
        Wt2[nn * 128 + kk] = f2b(W2[i]);
    }
}

// ---------------- MFMA GEMM: Hb[n x 128](bf16) = X[n x 128](fp32) @ W ----------------
__global__ __launch_bounds__(256) void k_gemm(const float* __restrict__ X, const ushort* __restrict__ Wt,
                                              ushort* __restrict__ Hb, int nrows) {
    const int wave = threadIdx.x >> 6;
    const int lane = threadIdx.x & 63;
    const int quad = lane >> 4;
    const int m = lane & 15;
    const int row0 = blockIdx.x * 64 + wave * 16;
    const int rowc = min(row0 + m, nrows - 1);

    f32x4 acc[8];
    #pragma unroll
    for (int t = 0; t < 8; t++) acc[t] = (f32x4){0.f, 0.f, 0.f, 0.f};

    #pragma unroll
    for (int ks = 0; ks < 4; ks++) {
        const int k0 = ks * 32 + quad * 8;
        const float* p = X + (size_t)rowc * D + k0;
        float4 u0 = ((const float4*)p)[0];
        float4 u1 = ((const float4*)p)[1];
        short8 a;
        a[0] = (short)f2b(u0.x); a[1] = (short)f2b(u0.y);
        a[2] = (short)f2b(u0.z); a[3] = (short)f2b(u0.w);
        a[4] = (short)f2b(u1.x); a[5] = (short)f2b(u1.y);
        a[6] = (short)f2b(u1.z); a[7] = (short)f2b(u1.w);
        #pragma unroll
        for (int t = 0; t < 8; t++) {
            short8 b = *(const short8*)(Wt + ((t * 16 + m) * D + k0));
            acc[t] = __builtin_amdgcn_mfma_f32_16x16x32_bf16(a, b, acc[t], 0, 0, 0);
        }
    }
    #pragma unroll
    for (int r = 0; r < 4; r++) {
        int orow = row0 + quad * 4 + r;
        if (orow < nrows) {
            #pragma unroll
            for (int t = 0; t < 8; t++)
                Hb[(size_t)orow * D + t * 16 + m] = f2b(acc[t][r]);
        }
    }
}

// ---------------- CSR aggregation (bf16 gather, fp32 accumulate) ----------------
template <bool RELU>
__global__ __launch_bounds__(256) void k_agg(const ushort* __restrict__ Hb, const float* __restrict__ dinv,
                                             const int* __restrict__ rowptr, const int2* __restrict__ epack,
                                             const float* __restrict__ bias, float* __restrict__ out, int n) {
    int v = blockIdx.x * 4 + (threadIdx.x >> 6);
    int lane = threadIdx.x & 63;
    if (v >= n) return;
    float dv = dinv[v];
    const uint* __restrict__ Hu = (const uint*)Hb;
    uint hs = Hu[(size_t)v * 64 + lane];
    float ax = dv * __uint_as_float(hs << 16);
    float ay = dv * __uint_as_float(hs & 0xffff0000u);
    int e = rowptr[v];
    const int end = rowptr[v + 1];
    for (; e + 7 < end; e += 8) {
        int2 p[8];
        #pragma unroll
        for (int i = 0; i < 8; i++) p[i] = epack[e + i];
        uint h[8];
        #pragma unroll
        for (int i = 0; i < 8; i++) h[i] = Hu[(size_t)p[i].x * 64 + lane];
        #pragma unroll
        for (int i = 0; i < 8; i++) {
            float w = __int_as_float(p[i].y);
            ax += w * __uint_as_float(h[i] << 16);
            ay += w * __uint_as_float(h[i] & 0xffff0000u);
        }
    }
    for (; e + 3 < end; e += 4) {
        int2 p[4];
        #pragma unroll
        for (int i = 0; i < 4; i++) p[i] = epack[e + i];
        uint h[4];
        #pragma unroll
        for (int i = 0; i < 4; i++) h[i] = Hu[(size_t)p[i].x * 64 + lane];
        #pragma unroll
        for (int i = 0; i < 4; i++) {
            float w = __int_as_float(p[i].y);
            ax += w * __uint_as_float(h[i] << 16);
            ay += w * __uint_as_float(h[i] & 0xffff0000u);
        }
    }
    for (; e < end; ++e) {
        int2 pp = epack[e];
        uint hh = Hu[(size_t)pp.x * 64 + lane];
        float w = __int_as_float(pp.y);
        ax += w * __uint_as_float(hh << 16);
        ay += w * __uint_as_float(hh & 0xffff0000u);
    }
    float2 bb = ((const float2*)bias)[lane];
    float rx = dv * ax + bb.x;
    float ry = dv * ay + bb.y;
    if (RELU) { rx = fmaxf(rx, 0.f); ry = fmaxf(ry, 0.f); }
    ((float2*)(out + (size_t)v * D))[lane] = make_float2(rx, ry);
}

// ---------------- launcher ----------------

static inline size_t alignup(size_t x) { return (x + 511) & ~(size_t)511; }

extern "C" void kernel_launch(void* const* d_in, const int* in_sizes, int n_in,
                              void* d_out, int out_size, void* d_ws, size_t ws_size,
                              hipStream_t stream) {
    const float* x  = (const float*)d_in[0];
    const int* eidx = (const int*)d_in[1];   // [2,E]: src row, dst row (int32)
    const float* W1 = (const float*)d_in[2];
    const float* b1 = (const float*)d_in[3];
    const float* W2 = (const float*)d_in[4];
    const float* b2 = (const float*)d_in[5];
    float* out = (float*)d_out;

    const int N = in_sizes[0] / D;
    const int E = in_sizes[1] / 2;
    const int* src = eidx;
    const int* dst = eidx + E;
    const int nbuk = (N + BUKSZ - 1) >> BUKBITS;   // 782

    // workspace
    char* ws = (char*)d_ws;
    size_t off = 0;
    int* counts = (int*)(ws + off);   off = alignup(off + (size_t)N * 4);
    int* rowptr = (int*)(ws + off);   off = alignup(off + (size_t)(N + 1) * 4);
    int* bsum   = (int*)(ws + off);   off = alignup(off + 256 * 4);
    float* dinv = (float*)(ws + off); off = alignup(off + (size_t)N * 4);
    int* gcur   = (int*)(ws + off);   off = alignup(off + (size_t)MAXBUK * 4);
    int2* epack = (int2*)(ws + off);  off = alignup(off + (size_t)E * 8);
    ushort* hbuf = (ushort*)(ws + off); off = alignup(off + (size_t)N * D * 2);
    ushort* Wt1 = (ushort*)(ws + off); off = alignup(off + 16384 * 2);
    ushort* Wt2 = (ushort*)(ws + off); off = alignup(off + 16384 * 2);
    uint* tmp = (uint*)hbuf;  // E uints (6.4 MB) alias hbuf; dead before gemm1 writes
    (void)ws_size;

    const int nT = 256;
    const int nScan = (N + 4095) / 4096;
    const int gE4 = (E / 4 + nT - 1) / nT;
    const int gScat = (E + 256 * SC_ITER - 1) / (256 * SC_ITER);  // 391

    hipMemsetAsync(counts, 0, (size_t)N * 4, stream);
    k_prepW<<<64, nT, 0, stream>>>(W1, W2, Wt1, Wt2);
    k_hist<<<gE4, nT, 0, stream>>>(dst, counts, E);
    k_scan1<<<nScan, nT, 0, stream>>>(counts, bsum, N);
    k_scan2<<<1, 64, 0, stream>>>(bsum, nScan, rowptr, N);
    k_scan3<<<nScan, nT, 0, stream>>>(counts, bsum, rowptr, dinv, N);
    k_gcur<<<(nbuk + nT - 1) / nT, nT, 0, stream>>>(rowptr, gcur, nbuk);
    k_scatter<<<gScat, nT, 0, stream>>>(src, dst, gcur, tmp, E, nbuk);
    k_fillC<<<nbuk, nT, 0, stream>>>(tmp, rowptr, dinv, epack, N);

    const int gGemm = (N + 63) / 64;
    const int gAgg = (N + 3) / 4;

    // layer 1: hbuf = bf16(x @ W1); d_out(temp fp32) = relu(agg(hbuf) + b1)
    k_gemm<<<gGemm, nT, 0, stream>>>(x, Wt1, hbuf, N);
    k_agg<true><<<gAgg, nT, 0, stream>>>(hbuf, dinv, rowptr, epack, b1, out, N);

    // layer 2: hbuf = bf16(out @ W2); out = agg(hbuf) + b2
    k_gemm<<<gGemm, nT, 0, stream>>>(out, Wt2, hbuf, N);
    k_agg<false><<<gAgg, nT, 0, stream>>>(hbuf, dinv, rowptr, epack, b2, out, N);
}

// Round 5
// 379.093 us; speedup vs baseline: 2.0856x; 1.1560x over previous
//
#include <hip/hip_runtime.h>
#include <hip/hip_bf16.h>

// GCN 2-layer. agg[v] = dinv[v]*(dinv[v]*h[v] + sum_e dinv[src]*h[src]) + b
// CSR via bucket-binned counting sort; rowptr/dinv computed bucket-locally
// (no global per-node counts/scan). GEMMs via bf16 MFMA 16x16x32.

#define D 128
#define BUKBITS 7          // 128 nodes per bucket
#define BUKSZ 128
#define MAXBUK 1024        // supports N <= 131072 (and src < 2^25 packing)
#define SCHUNK 16384       // edges per scatter/hist block

typedef __attribute__((ext_vector_type(8))) short short8;
typedef __attribute__((ext_vector_type(4))) float f32x4;

static __device__ __forceinline__ ushort f2b(float f) {
    __hip_bfloat16 h = __float2bfloat16(f);
    return *reinterpret_cast<ushort*>(&h);
}

// ---------------- CSR build ----------------

// bucket-granular histogram: bukcnt[b] += #edges with dst in bucket b
__global__ __launch_bounds__(256) void k_bukhist(const int* __restrict__ dst, int* __restrict__ bukcnt,
                                                 int E, int nbuk) {
    __shared__ int lh[MAXBUK];
    for (int i = threadIdx.x; i < nbuk; i += 256) lh[i] = 0;
    __syncthreads();
    int start = blockIdx.x * SCHUNK;
    int end = min(E, start + SCHUNK);
    for (int e = start + threadIdx.x; e < end; e += 256)
        atomicAdd(&lh[dst[e] >> BUKBITS], 1);
    __syncthreads();
    for (int i = threadIdx.x; i < nbuk; i += 256)
        if (lh[i]) atomicAdd(&bukcnt[i], lh[i]);
}

// one-block exclusive scan of bukcnt -> bukbase (nbuk+1) and gcur
__global__ __launch_bounds__(256) void k_bukscan(const int* __restrict__ bukcnt, int* __restrict__ bukbase,
                                                 int* __restrict__ gcur, int nbuk, int E) {
    __shared__ int vals[MAXBUK];
    __shared__ int tsum[256];
    int t = threadIdx.x;
    for (int i = t; i < MAXBUK; i += 256) vals[i] = (i < nbuk) ? bukcnt[i] : 0;
    __syncthreads();
    int o = t * 4;
    int s = vals[o] + vals[o + 1] + vals[o + 2] + vals[o + 3];
    tsum[t] = s;
    __syncthreads();
    for (int off = 1; off < 256; off <<= 1) {
        int v = (t >= off) ? tsum[t - off] : 0;
        __syncthreads();
        tsum[t] += v;
        __syncthreads();
    }
    int run = tsum[t] - s;  // exclusive prefix of this thread's chunk
    for (int i = 0; i < 4; i++) {
        int idx = o + i;
        if (idx < nbuk) { bukbase[idx] = run; gcur[idx] = run; }
        run += vals[idx];
    }
    if (t == 0) bukbase[nbuk] = E;
}

// edges -> bucket-grouped tmp via LDS hist + global range reservation (two-pass)
// tmp payload: (dstLow << 25) | src
__global__ __launch_bounds__(256) void k_scatter(const int* __restrict__ src, const int* __restrict__ dst,
                                                 int* __restrict__ gcur, uint* __restrict__ tmp,
                                                 int E, int nbuk) {
    __shared__ int lh[MAXBUK];
    __shared__ int lbase[MAXBUK];
    for (int i = threadIdx.x; i < nbuk; i += 256) lh[i] = 0;
    __syncthreads();
    int start = blockIdx.x * SCHUNK;
    int end = min(E, start + SCHUNK);
    for (int e = start + threadIdx.x; e < end; e += 256)
        atomicAdd(&lh[dst[e] >> BUKBITS], 1);
    __syncthreads();
    for (int i = threadIdx.x; i < nbuk; i += 256) {
        int c = lh[i];
        lbase[i] = c ? atomicAdd(&gcur[i], c) : 0;
        lh[i] = 0;  // reuse as placement cursor
    }
    __syncthreads();
    for (int e = start + threadIdx.x; e < end; e += 256) {
        int s = src[e];
        int d = dst[e];
        int bk = d >> BUKBITS;
        int r = atomicAdd(&lh[bk], 1);
        tmp[lbase[bk] + r] = ((uint)(d & (BUKSZ - 1)) << 25) | (uint)s;
    }
}

// bucket-local: count per-node, LDS scan -> rowptr+dinv, place eord (src-permuted)
__global__ __launch_bounds__(256) void k_fillC(const uint* __restrict__ tmp, const int* __restrict__ bukbase,
                                               int* __restrict__ eord, int* __restrict__ rowptr,
                                               float* __restrict__ dinv, int n, int nbuk) {
    __shared__ int cnt[BUKSZ];
    __shared__ int sc[BUKSZ];
    __shared__ int lrp[BUKSZ];
    int b = blockIdx.x;
    int node0 = b << BUKBITS;
    int nn = min(BUKSZ, n - node0);
    int e0 = bukbase[b], e1 = bukbase[b + 1];
    int t = threadIdx.x;
    if (t < BUKSZ) cnt[t] = 0;
    __syncthreads();
    for (int e = e0 + t; e < e1; e += 256)
        atomicAdd(&cnt[tmp[e] >> 25], 1);
    __syncthreads();
    int c0 = (t < BUKSZ) ? cnt[t] : 0;
    if (t < BUKSZ) sc[t] = c0;
    __syncthreads();
    for (int off = 1; off < BUKSZ; off <<= 1) {
        int v = (t < BUKSZ && t >= off) ? sc[t - off] : 0;
        __syncthreads();
        if (t < BUKSZ) sc[t] += v;
        __syncthreads();
    }
    if (t < BUKSZ) lrp[t] = e0 + sc[t] - c0;   // node's edge base
    if (t < nn) {
        rowptr[node0 + t] = e0 + sc[t] - c0;
        dinv[node0 + t] = 1.0f / sqrtf((float)(c0 + 1));  // +1 self-loop
    }
    if (b == nbuk - 1 && t == 0) rowptr[n] = e1;
    __syncthreads();
    if (t < BUKSZ) cnt[t] = 0;
    __syncthreads();
    for (int e = e0 + t; e < e1; e += 256) {
        uint u = tmp[e];
        int dL = (int)(u >> 25);
        int s = (int)(u & 0x1FFFFFFu);
        int r = atomicAdd(&cnt[dL], 1);
        eord[lrp[dL] + r] = s;
    }
}

// ---------------- W prep: transpose + bf16 (Wt[n][k]) ----------------
__global__ __launch_bounds__(256) void k_prepW(const float* __restrict__ W1, const float* __restrict__ W2,
                                               ushort* __restrict__ Wt1, ushort* __restrict__ Wt2) {
    int i = blockIdx.x * 256 + threadIdx.x;
    if (i < 16384) {
        int kk = i >> 7, nn = i & 127;
        Wt1[nn * 128 + kk] = f2b(W1[i]);
        Wt2[nn * 128 + kk] = f2b(W2[i]);
    }
}

// ---------------- MFMA GEMM: Hb[n x 128](bf16) = X[n x 128](fp32) @ W ----------------
__global__ __launch_bounds__(256) void k_gemm(const float* __restrict__ X, const ushort* __restrict__ Wt,
                                              ushort* __restrict__ Hb, int nrows) {
    const int wave = threadIdx.x >> 6;
    const int lane = threadIdx.x & 63;
    const int quad = lane >> 4;
    const int m = lane & 15;
    const int row0 = blockIdx.x * 64 + wave * 16;
    const int rowc = min(row0 + m, nrows - 1);

    f32x4 acc[8];
    #pragma unroll
    for (int t = 0; t < 8; t++) acc[t] = (f32x4){0.f, 0.f, 0.f, 0.f};

    #pragma unroll
    for (int ks = 0; ks < 4; ks++) {
        const int k0 = ks * 32 + quad * 8;
        const float* p = X + (size_t)rowc * D + k0;
        float4 u0 = ((const float4*)p)[0];
        float4 u1 = ((const float4*)p)[1];
        short8 a;
        a[0] = (short)f2b(u0.x); a[1] = (short)f2b(u0.y);
        a[2] = (short)f2b(u0.z); a[3] = (short)f2b(u0.w);
        a[4] = (short)f2b(u1.x); a[5] = (short)f2b(u1.y);
        a[6] = (short)f2b(u1.z); a[7] = (short)f2b(u1.w);
        #pragma unroll
        for (int t = 0; t < 8; t++) {
            short8 b = *(const short8*)(Wt + ((t * 16 + m) * D + k0));
            acc[t] = __builtin_amdgcn_mfma_f32_16x16x32_bf16(a, b, acc[t], 0, 0, 0);
        }
    }
    #pragma unroll
    for (int r = 0; r < 4; r++) {
        int orow = row0 + quad * 4 + r;
        if (orow < nrows) {
            #pragma unroll
            for (int t = 0; t < 8; t++)
                Hb[(size_t)orow * D + t * 16 + m] = f2b(acc[t][r]);
        }
    }
}

// ---------------- CSR aggregation (bf16 gather, fp32 accumulate) ----------------
template <bool RELU>
__global__ __launch_bounds__(256) void k_agg(const ushort* __restrict__ Hb, const float* __restrict__ dinv,
                                             const int* __restrict__ rowptr, const int* __restrict__ eord,
                                             const float* __restrict__ bias, float* __restrict__ out, int n) {
    int v = blockIdx.x * 4 + (threadIdx.x >> 6);
    int lane = threadIdx.x & 63;
    if (v >= n) return;
    float dv = dinv[v];
    const uint* __restrict__ Hu = (const uint*)Hb;
    uint hs = Hu[(size_t)v * 64 + lane];
    float ax = dv * __uint_as_float(hs << 16);
    float ay = dv * __uint_as_float(hs & 0xffff0000u);
    int e = rowptr[v];
    const int end = rowptr[v + 1];
    for (; e + 7 < end; e += 8) {
        int s[8];
        #pragma unroll
        for (int i = 0; i < 8; i++) s[i] = eord[e + i];
        float w[8];
        uint h[8];
        #pragma unroll
        for (int i = 0; i < 8; i++) w[i] = dinv[s[i]];
        #pragma unroll
        for (int i = 0; i < 8; i++) h[i] = Hu[(size_t)s[i] * 64 + lane];
        #pragma unroll
        for (int i = 0; i < 8; i++) {
            ax += w[i] * __uint_as_float(h[i] << 16);
            ay += w[i] * __uint_as_float(h[i] & 0xffff0000u);
        }
    }
    for (; e + 3 < end; e += 4) {
        int s[4];
        #pragma unroll
        for (int i = 0; i < 4; i++) s[i] = eord[e + i];
        float w[4];
        uint h[4];
        #pragma unroll
        for (int i = 0; i < 4; i++) w[i] = dinv[s[i]];
        #pragma unroll
        for (int i = 0; i < 4; i++) h[i] = Hu[(size_t)s[i] * 64 + lane];
        #pragma unroll
        for (int i = 0; i < 4; i++) {
            ax += w[i] * __uint_as_float(h[i] << 16);
            ay += w[i] * __uint_as_float(h[i] & 0xffff0000u);
        }
    }
    for (; e < end; ++e) {
        int s = eord[e];
        float w = dinv[s];
        uint hh = Hu[(size_t)s * 64 + lane];
        ax += w * __uint_as_float(hh << 16);
        ay += w * __uint_as_float(hh & 0xffff0000u);
    }
    float2 bb = ((const float2*)bias)[lane];
    float rx = dv * ax + bb.x;
    float ry = dv * ay + bb.y;
    if (RELU) { rx = fmaxf(rx, 0.f); ry = fmaxf(ry, 0.f); }
    ((float2*)(out + (size_t)v * D))[lane] = make_float2(rx, ry);
}

// ---------------- launcher ----------------

static inline size_t alignup(size_t x) { return (x + 511) & ~(size_t)511; }

extern "C" void kernel_launch(void* const* d_in, const int* in_sizes, int n_in,
                              void* d_out, int out_size, void* d_ws, size_t ws_size,
                              hipStream_t stream) {
    const float* x  = (const float*)d_in[0];
    const int* eidx = (const int*)d_in[1];   // [2,E]: src row, dst row (int32)
    const float* W1 = (const float*)d_in[2];
    const float* b1 = (const float*)d_in[3];
    const float* W2 = (const float*)d_in[4];
    const float* b2 = (const float*)d_in[5];
    float* out = (float*)d_out;

    const int N = in_sizes[0] / D;
    const int E = in_sizes[1] / 2;
    const int* src = eidx;
    const int* dst = eidx + E;
    const int nbuk = (N + BUKSZ - 1) >> BUKBITS;   // 782

    // workspace
    char* ws = (char*)d_ws;
    size_t off = 0;
    int* bukcnt = (int*)(ws + off);   off = alignup(off + (size_t)MAXBUK * 4);
    int* bukbase = (int*)(ws + off);  off = alignup(off + (size_t)(MAXBUK + 1) * 4);
    int* gcur   = (int*)(ws + off);   off = alignup(off + (size_t)MAXBUK * 4);
    int* rowptr = (int*)(ws + off);   off = alignup(off + (size_t)(N + 1) * 4);
    float* dinv = (float*)(ws + off); off = alignup(off + (size_t)N * 4);
    int* eord   = (int*)(ws + off);   off = alignup(off + (size_t)E * 4);
    ushort* hbuf = (ushort*)(ws + off); off = alignup(off + (size_t)N * D * 2);
    ushort* Wt1 = (ushort*)(ws + off); off = alignup(off + 16384 * 2);
    ushort* Wt2 = (ushort*)(ws + off); off = alignup(off + 16384 * 2);
    uint* tmp = (uint*)hbuf;  // E uints (6.4 MB) alias hbuf; dead before gemm1 writes
    (void)ws_size;

    const int nT = 256;
    const int gChunk = (E + SCHUNK - 1) / SCHUNK;   // 98

    hipMemsetAsync(bukcnt, 0, (size_t)MAXBUK * 4, stream);
    k_prepW<<<64, nT, 0, stream>>>(W1, W2, Wt1, Wt2);
    k_bukhist<<<gChunk, nT, 0, stream>>>(dst, bukcnt, E, nbuk);
    k_bukscan<<<1, nT, 0, stream>>>(bukcnt, bukbase, gcur, nbuk, E);
    k_scatter<<<gChunk, nT, 0, stream>>>(src, dst, gcur, tmp, E, nbuk);
    k_fillC<<<nbuk, nT, 0, stream>>>(tmp, bukbase, eord, rowptr, dinv, N, nbuk);

    const int gGemm = (N + 63) / 64;
    const int gAgg = (N + 3) / 4;

    // layer 1: hbuf = bf16(x @ W1); d_out(temp fp32) = relu(agg(hbuf) + b1)
    k_gemm<<<gGemm, nT, 0, stream>>>(x, Wt1, hbuf, N);
    k_agg<true><<<gAgg, nT, 0, stream>>>(hbuf, dinv, rowptr, eord, b1, out, N);

    // layer 2: hbuf = bf16(out @ W2); out = agg(hbuf) + b2
    k_gemm<<<gGemm, nT, 0, stream>>>(out, Wt2, hbuf, N);
    k_agg<false><<<gAgg, nT, 0, stream>>>(hbuf, dinv, rowptr, eord, b2, out, N);
}

// Round 6
// 368.878 us; speedup vs baseline: 2.1434x; 1.0277x over previous
//
#include <hip/hip_runtime.h>
#include <hip/hip_bf16.h>

// GCN 2-layer. With prescaled rows h'[v]=dinv[v]*h[v]:
//   agg[v] = dinv[v]*(h'[v] + sum_e h'[src_e]) + b
// CSR via bucket-binned counting sort (bucket-local rowptr/dinv).
// GEMMs via bf16 MFMA 16x16x32, epilogue scales by dinv and stores bf16.
// Layer-1 activation kept bf16 (identical rounding to the old fp32->bf16 path).

#define D 128
#define BUKBITS 7          // 128 nodes per bucket
#define BUKSZ 128
#define MAXBUK 1024        // supports N <= 131072 (src < 2^25 packing)
#define SCHUNK 16384       // edges per scatter/hist block

typedef __attribute__((ext_vector_type(8))) short short8;
typedef __attribute__((ext_vector_type(4))) float f32x4;

static __device__ __forceinline__ ushort f2b(float f) {
    __hip_bfloat16 h = __float2bfloat16(f);
    return *reinterpret_cast<ushort*>(&h);
}

// ---------------- CSR build ----------------

__global__ __launch_bounds__(256) void k_bukhist(const int* __restrict__ dst, int* __restrict__ bukcnt,
                                                 int E, int nbuk) {
    __shared__ int lh[MAXBUK];
    for (int i = threadIdx.x; i < nbuk; i += 256) lh[i] = 0;
    __syncthreads();
    int start = blockIdx.x * SCHUNK;
    int end = min(E, start + SCHUNK);
    for (int e = start + threadIdx.x; e < end; e += 256)
        atomicAdd(&lh[dst[e] >> BUKBITS], 1);
    __syncthreads();
    for (int i = threadIdx.x; i < nbuk; i += 256)
        if (lh[i]) atomicAdd(&bukcnt[i], lh[i]);
}

__global__ __launch_bounds__(256) void k_bukscan(const int* __restrict__ bukcnt, int* __restrict__ bukbase,
                                                 int* __restrict__ gcur, int nbuk, int E) {
    __shared__ int vals[MAXBUK];
    __shared__ int tsum[256];
    int t = threadIdx.x;
    for (int i = t; i < MAXBUK; i += 256) vals[i] = (i < nbuk) ? bukcnt[i] : 0;
    __syncthreads();
    int o = t * 4;
    int s = vals[o] + vals[o + 1] + vals[o + 2] + vals[o + 3];
    tsum[t] = s;
    __syncthreads();
    for (int off = 1; off < 256; off <<= 1) {
        int v = (t >= off) ? tsum[t - off] : 0;
        __syncthreads();
        tsum[t] += v;
        __syncthreads();
    }
    int run = tsum[t] - s;
    for (int i = 0; i < 4; i++) {
        int idx = o + i;
        if (idx < nbuk) { bukbase[idx] = run; gcur[idx] = run; }
        run += vals[idx];
    }
    if (t == 0) bukbase[nbuk] = E;
}

// edges -> bucket-grouped tmp: (dstLow << 25) | src
__global__ __launch_bounds__(256) void k_scatter(const int* __restrict__ src, const int* __restrict__ dst,
                                                 int* __restrict__ gcur, uint* __restrict__ tmp,
                                                 int E, int nbuk) {
    __shared__ int lh[MAXBUK];
    __shared__ int lbase[MAXBUK];
    for (int i = threadIdx.x; i < nbuk; i += 256) lh[i] = 0;
    __syncthreads();
    int start = blockIdx.x * SCHUNK;
    int end = min(E, start + SCHUNK);
    for (int e = start + threadIdx.x; e < end; e += 256)
        atomicAdd(&lh[dst[e] >> BUKBITS], 1);
    __syncthreads();
    for (int i = threadIdx.x; i < nbuk; i += 256) {
        int c = lh[i];
        lbase[i] = c ? atomicAdd(&gcur[i], c) : 0;
        lh[i] = 0;
    }
    __syncthreads();
    for (int e = start + threadIdx.x; e < end; e += 256) {
        int s = src[e];
        int d = dst[e];
        int bk = d >> BUKBITS;
        int r = atomicAdd(&lh[bk], 1);
        tmp[lbase[bk] + r] = ((uint)(d & (BUKSZ - 1)) << 25) | (uint)s;
    }
}

// bucket-local: per-node count, LDS scan -> rowptr+dinv, place eord
__global__ __launch_bounds__(256) void k_fillC(const uint* __restrict__ tmp, const int* __restrict__ bukbase,
                                               int* __restrict__ eord, int* __restrict__ rowptr,
                                               float* __restrict__ dinv, int n, int nbuk) {
    __shared__ int cnt[BUKSZ];
    __shared__ int sc[BUKSZ];
    __shared__ int lrp[BUKSZ];
    int b = blockIdx.x;
    int node0 = b << BUKBITS;
    int nn = min(BUKSZ, n - node0);
    int e0 = bukbase[b], e1 = bukbase[b + 1];
    int t = threadIdx.x;
    if (t < BUKSZ) cnt[t] = 0;
    __syncthreads();
    for (int e = e0 + t; e < e1; e += 256)
        atomicAdd(&cnt[tmp[e] >> 25], 1);
    __syncthreads();
    int c0 = (t < BUKSZ) ? cnt[t] : 0;
    if (t < BUKSZ) sc[t] = c0;
    __syncthreads();
    for (int off = 1; off < BUKSZ; off <<= 1) {
        int v = (t < BUKSZ && t >= off) ? sc[t - off] : 0;
        __syncthreads();
        if (t < BUKSZ) sc[t] += v;
        __syncthreads();
    }
    if (t < BUKSZ) lrp[t] = e0 + sc[t] - c0;
    if (t < nn) {
        rowptr[node0 + t] = e0 + sc[t] - c0;
        dinv[node0 + t] = 1.0f / sqrtf((float)(c0 + 1));  // +1 self-loop
    }
    if (b == nbuk - 1 && t == 0) rowptr[n] = e1;
    __syncthreads();
    if (t < BUKSZ) cnt[t] = 0;
    __syncthreads();
    for (int e = e0 + t; e < e1; e += 256) {
        uint u = tmp[e];
        int dL = (int)(u >> 25);
        int s = (int)(u & 0x1FFFFFFu);
        int r = atomicAdd(&cnt[dL], 1);
        eord[lrp[dL] + r] = s;
    }
}

// ---------------- W prep: transpose + bf16 (Wt[n][k]) ----------------
__global__ __launch_bounds__(256) void k_prepW(const float* __restrict__ W1, const float* __restrict__ W2,
                                               ushort* __restrict__ Wt1, ushort* __restrict__ Wt2) {
    int i = blockIdx.x * 256 + threadIdx.x;
    if (i < 16384) {
        int kk = i >> 7, nn = i & 127;
        Wt1[nn * 128 + kk] = f2b(W1[i]);
        Wt2[nn * 128 + kk] = f2b(W2[i]);
    }
}

// ---------------- MFMA GEMM: Hb[row] = bf16(dinv[row] * (X[row] @ W)) ----------------
// A fp32 (layer1) or bf16 (layer2). Layouts (verified):
// A[m=lane&15][k=quad*8+j]; B[k][n=lane&15]; D col=lane&15, row=quad*4+r
template <bool ABF16>
__global__ __launch_bounds__(256) void k_gemm(const void* __restrict__ Xv, const ushort* __restrict__ Wt,
                                              const float* __restrict__ dinv, ushort* __restrict__ Hb,
                                              int nrows) {
    const int wave = threadIdx.x >> 6;
    const int lane = threadIdx.x & 63;
    const int quad = lane >> 4;
    const int m = lane & 15;
    const int row0 = blockIdx.x * 64 + wave * 16;
    const int rowc = min(row0 + m, nrows - 1);

    f32x4 acc[8];
    #pragma unroll
    for (int t = 0; t < 8; t++) acc[t] = (f32x4){0.f, 0.f, 0.f, 0.f};

    #pragma unroll
    for (int ks = 0; ks < 4; ks++) {
        const int k0 = ks * 32 + quad * 8;
        short8 a;
        if (ABF16) {
            a = *(const short8*)((const ushort*)Xv + (size_t)rowc * D + k0);
        } else {
            const float* p = (const float*)Xv + (size_t)rowc * D + k0;
            float4 u0 = ((const float4*)p)[0];
            float4 u1 = ((const float4*)p)[1];
            a[0] = (short)f2b(u0.x); a[1] = (short)f2b(u0.y);
            a[2] = (short)f2b(u0.z); a[3] = (short)f2b(u0.w);
            a[4] = (short)f2b(u1.x); a[5] = (short)f2b(u1.y);
            a[6] = (short)f2b(u1.z); a[7] = (short)f2b(u1.w);
        }
        #pragma unroll
        for (int t = 0; t < 8; t++) {
            short8 b = *(const short8*)(Wt + ((t * 16 + m) * D + k0));
            acc[t] = __builtin_amdgcn_mfma_f32_16x16x32_bf16(a, b, acc[t], 0, 0, 0);
        }
    }
    #pragma unroll
    for (int r = 0; r < 4; r++) {
        int orow = row0 + quad * 4 + r;
        if (orow < nrows) {
            float dvv = dinv[orow];
            #pragma unroll
            for (int t = 0; t < 8; t++)
                Hb[(size_t)orow * D + t * 16 + m] = f2b(acc[t][r] * dvv);
        }
    }
}

// ---------------- CSR aggregation: out[v] = dv*(h'[v]+sum h'[s]) + b ----------------
// one node per 64-lane wave; lane owns dims {2*lane, 2*lane+1} (one bf16x2 word).
template <bool RELU, bool OBF16>
__global__ __launch_bounds__(256) void k_agg(const ushort* __restrict__ Hb, const float* __restrict__ dinv,
                                             const int* __restrict__ rowptr, const int* __restrict__ eord,
                                             const float* __restrict__ bias, void* __restrict__ outp, int n) {
    int v = blockIdx.x * 4 + (threadIdx.x >> 6);
    int lane = threadIdx.x & 63;
    if (v >= n) return;
    float dv = dinv[v];
    const uint* __restrict__ Hu = (const uint*)Hb;
    uint hs = Hu[(size_t)v * 64 + lane];
    float ax = __uint_as_float(hs << 16);
    float ay = __uint_as_float(hs & 0xffff0000u);
    int e = rowptr[v];
    const int end = rowptr[v + 1];
    for (; e + 15 < end; e += 16) {
        int s[16];
        #pragma unroll
        for (int i = 0; i < 16; i++) s[i] = eord[e + i];
        uint h[16];
        #pragma unroll
        for (int i = 0; i < 16; i++) h[i] = Hu[(size_t)s[i] * 64 + lane];
        #pragma unroll
        for (int i = 0; i < 16; i++) {
            ax += __uint_as_float(h[i] << 16);
            ay += __uint_as_float(h[i] & 0xffff0000u);
        }
    }
    for (; e + 3 < end; e += 4) {
        int s[4];
        #pragma unroll
        for (int i = 0; i < 4; i++) s[i] = eord[e + i];
        uint h[4];
        #pragma unroll
        for (int i = 0; i < 4; i++) h[i] = Hu[(size_t)s[i] * 64 + lane];
        #pragma unroll
        for (int i = 0; i < 4; i++) {
            ax += __uint_as_float(h[i] << 16);
            ay += __uint_as_float(h[i] & 0xffff0000u);
        }
    }
    for (; e < end; ++e) {
        uint hh = Hu[(size_t)eord[e] * 64 + lane];
        ax += __uint_as_float(hh << 16);
        ay += __uint_as_float(hh & 0xffff0000u);
    }
    float2 bb = ((const float2*)bias)[lane];
    float rx = dv * ax + bb.x;
    float ry = dv * ay + bb.y;
    if (RELU) { rx = fmaxf(rx, 0.f); ry = fmaxf(ry, 0.f); }
    if (OBF16) {
        uint w = ((uint)f2b(ry) << 16) | (uint)f2b(rx);
        ((uint*)outp)[(size_t)v * 64 + lane] = w;
    } else {
        ((float2*)((float*)outp + (size_t)v * D))[lane] = make_float2(rx, ry);
    }
}

// ---------------- launcher ----------------

static inline size_t alignup(size_t x) { return (x + 511) & ~(size_t)511; }

extern "C" void kernel_launch(void* const* d_in, const int* in_sizes, int n_in,
                              void* d_out, int out_size, void* d_ws, size_t ws_size,
                              hipStream_t stream) {
    const float* x  = (const float*)d_in[0];
    const int* eidx = (const int*)d_in[1];   // [2,E]: src row, dst row (int32)
    const float* W1 = (const float*)d_in[2];
    const float* b1 = (const float*)d_in[3];
    const float* W2 = (const float*)d_in[4];
    const float* b2 = (const float*)d_in[5];
    float* out = (float*)d_out;

    const int N = in_sizes[0] / D;
    const int E = in_sizes[1] / 2;
    const int* src = eidx;
    const int* dst = eidx + E;
    const int nbuk = (N + BUKSZ - 1) >> BUKBITS;   // 782

    // workspace
    char* ws = (char*)d_ws;
    size_t off = 0;
    int* bukcnt = (int*)(ws + off);   off = alignup(off + (size_t)MAXBUK * 4);
    int* bukbase = (int*)(ws + off);  off = alignup(off + (size_t)(MAXBUK + 1) * 4);
    int* gcur   = (int*)(ws + off);   off = alignup(off + (size_t)MAXBUK * 4);
    int* rowptr = (int*)(ws + off);   off = alignup(off + (size_t)(N + 1) * 4);
    float* dinv = (float*)(ws + off); off = alignup(off + (size_t)N * 4);
    int* eord   = (int*)(ws + off);   off = alignup(off + (size_t)E * 4);
    ushort* hbuf = (ushort*)(ws + off); off = alignup(off + (size_t)N * D * 2);
    ushort* act  = (ushort*)(ws + off); off = alignup(off + (size_t)N * D * 2);
    ushort* Wt1 = (ushort*)(ws + off); off = alignup(off + 16384 * 2);
    ushort* Wt2 = (ushort*)(ws + off); off = alignup(off + 16384 * 2);
    uint* tmp = (uint*)hbuf;  // E uints (6.4 MB) alias hbuf; dead before gemm1 writes
    (void)ws_size;

    const int nT = 256;
    const int gChunk = (E + SCHUNK - 1) / SCHUNK;   // 98

    hipMemsetAsync(bukcnt, 0, (size_t)MAXBUK * 4, stream);
    k_prepW<<<64, nT, 0, stream>>>(W1, W2, Wt1, Wt2);
    k_bukhist<<<gChunk, nT, 0, stream>>>(dst, bukcnt, E, nbuk);
    k_bukscan<<<1, nT, 0, stream>>>(bukcnt, bukbase, gcur, nbuk, E);
    k_scatter<<<gChunk, nT, 0, stream>>>(src, dst, gcur, tmp, E, nbuk);
    k_fillC<<<nbuk, nT, 0, stream>>>(tmp, bukbase, eord, rowptr, dinv, N, nbuk);

    const int gGemm = (N + 63) / 64;
    const int gAgg = (N + 3) / 4;

    // layer 1: hbuf = bf16(dinv*(x @ W1)); act(bf16) = relu(agg + b1)
    k_gemm<false><<<gGemm, nT, 0, stream>>>((const void*)x, Wt1, dinv, hbuf, N);
    k_agg<true, true><<<gAgg, nT, 0, stream>>>(hbuf, dinv, rowptr, eord, b1, (void*)act, N);

    // layer 2: hbuf = bf16(dinv*(act @ W2)); out(fp32) = agg + b2
    k_gemm<true><<<gGemm, nT, 0, stream>>>((const void*)act, Wt2, dinv, hbuf, N);
    k_agg<false, false><<<gAgg, nT, 0, stream>>>(hbuf, dinv, rowptr, eord, b2, (void*)out, N);
}